// Round 4
// baseline (708.002 us; speedup 1.0000x reference)
//
#include <hip/hip_runtime.h>
#include <hip/hip_bf16.h>

// Shapes: B=16, C=768, HW=4096.
#define BATCH 16
#define CDIM 768
#define NDIM 4096

typedef float  floatx4 __attribute__((ext_vector_type(4)));
typedef short  bf16x8  __attribute__((ext_vector_type(8)));

__device__ __forceinline__ short f2bf(float f) {
  unsigned u = __float_as_uint(f);
  unsigned r = (u + 0x7FFFu + ((u >> 16) & 1u)) >> 16;  // RNE
  return (short)r;
}

// async global->LDS, 16B per lane. LDS dest = wave-uniform base + lane*16.
__device__ __forceinline__ void gl_lds16(const short* g, short* l) {
  __builtin_amdgcn_global_load_lds(
      (const __attribute__((address_space(1))) unsigned int*)g,
      (__attribute__((address_space(3))) unsigned int*)l, 16, 0, 0);
}

// ---------------- kernel 0: zero S ----------------
__global__ __launch_bounds__(256) void k_zero(float* __restrict__ s) {
  size_t i = ((size_t)blockIdx.x * 256 + threadIdx.x) * 16;
  floatx4 z = {0.f, 0.f, 0.f, 0.f};
  floatx4* d = (floatx4*)(s + i);
  d[0] = z; d[1] = z; d[2] = z; d[3] = z;
}

// ---------------- kernel 1: fp32 -> bf16 elementwise ----------------
__global__ __launch_bounds__(256) void k_cvt(const float* __restrict__ x,
                                             short* __restrict__ xb) {
  size_t i = ((size_t)blockIdx.x * 256 + threadIdx.x) * 16;
  const floatx4* src = (const floatx4*)(x + i);
  floatx4 f0 = src[0], f1 = src[1], f2 = src[2], f3 = src[3];
  bf16x8 lo, hi;
#pragma unroll
  for (int j = 0; j < 4; j++) {
    lo[j]     = f2bf(f0[j]);
    lo[j + 4] = f2bf(f1[j]);
    hi[j]     = f2bf(f2[j]);
    hi[j + 4] = f2bf(f3[j]);
  }
  *(bf16x8*)(xb + i)     = lo;
  *(bf16x8*)(xb + i + 8) = hi;
}

// ---------------- kernel 2: tiled transpose fp32 -> bf16 ----------------
__global__ __launch_bounds__(256) void k_transpose(const float* __restrict__ X,
                                                   short* __restrict__ XT) {
  __shared__ __align__(16) short T[64][72];  // +8 pad
  int b = blockIdx.z;
  const float* Xb = X + (size_t)b * CDIM * NDIM;
  short* XTb = XT + (size_t)b * NDIM * CDIM;
  int r  = threadIdx.x >> 2;   // 0..63
  int cq = threadIdx.x & 3;    // 0..3 (16-col chunk)
  int gr  = blockIdx.y * 64 + r;         // c index
  int gc0 = blockIdx.x * 64 + cq * 16;   // n index base
  const floatx4* src = (const floatx4*)(Xb + (size_t)gr * NDIM + gc0);
  floatx4 f0 = src[0], f1 = src[1], f2 = src[2], f3 = src[3];
  bf16x8 lo, hi;
#pragma unroll
  for (int j = 0; j < 4; j++) {
    lo[j] = f2bf(f0[j]); lo[j + 4] = f2bf(f1[j]);
    hi[j] = f2bf(f2[j]); hi[j + 4] = f2bf(f3[j]);
  }
  *(bf16x8*)&T[r][cq * 16]     = lo;
  *(bf16x8*)&T[r][cq * 16 + 8] = hi;
  __syncthreads();
  bf16x8 o0, o1;
#pragma unroll
  for (int j = 0; j < 8; j++) o0[j] = T[cq * 16 + j][r];
#pragma unroll
  for (int j = 0; j < 8; j++) o1[j] = T[cq * 16 + 8 + j][r];
  short* dst = XTb + (size_t)(blockIdx.x * 64 + r) * CDIM + blockIdx.y * 64 + cq * 16;
  *(bf16x8*)dst       = o0;
  *(bf16x8*)(dst + 8) = o1;
}

// ---------------- kernel 3: bt-GEMM, 128x128 tile, BK=64, DMA staging ------
// C[m][n] += / = scale * sum_k A[m][k] * Bt[n][k]   (per batch, optional
// KSPLIT-way split-K with fp32 atomic accumulation).
// LDS: 8-row groups of 1024 B (DMA-contiguous), padded +64 B between groups
// (stride 1088 B = 544 shorts). Successive groups shift bank slots by 4, so
// fragment ds_read_b128 spreads 64 lanes as 8 per 4-bank slot = conflict-free.
template <int M, int N, int K, int KSPLIT, bool SCALE>
__global__ __launch_bounds__(256) void k_gemm(const short* __restrict__ A,
                                              const short* __restrict__ Bt,
                                              float* __restrict__ C,
                                              const float* __restrict__ gamma) {
  constexpr int GS = 544;           // shorts per 8-row group (1024 B + 64 B pad)
  constexpr int KC = K / KSPLIT;    // K per block
  __shared__ __align__(16) short Al[16 * GS];
  __shared__ __align__(16) short Bl[16 * GS];

  int b  = blockIdx.z / KSPLIT;
  int kc = blockIdx.z % KSPLIT;
  const short* Ab = A  + (size_t)b * M * K + kc * KC;
  const short* Bb = Bt + (size_t)b * N * K + kc * KC;
  float* Cb = C + (size_t)b * M * N;
  int tm = blockIdx.y, tn = blockIdx.x;

  int tid  = threadIdx.x;
  int lane = tid & 63;
  int wave = tid >> 6;
  int wm = (wave >> 1) * 64;
  int wn = (wave & 1) * 64;

  // DMA: wave covers rows [wave*32, +32) = groups [wave*4, +4), 4 issues.
  int lr = lane >> 3;    // row within 8-row issue
  int lc = lane & 7;     // 16B chunk within row
  const short* ga = Ab + (size_t)(tm * 128 + wave * 32 + lr) * K + lc * 8;
  const short* gb = Bb + (size_t)(tn * 128 + wave * 32 + lr) * K + lc * 8;
  short* la = Al + wave * 4 * GS;
  short* lb = Bl + wave * 4 * GS;

  floatx4 acc[4][4] = {};
  int row = lane & 15, quad = lane >> 4;

  for (int k0 = 0; k0 < KC; k0 += 64) {
    __syncthreads();  // previous iter's ds_reads done before overwrite
#pragma unroll
    for (int j = 0; j < 4; j++)
      gl_lds16(ga + (size_t)j * 8 * K, la + j * GS);
#pragma unroll
    for (int j = 0; j < 4; j++)
      gl_lds16(gb + (size_t)j * 8 * K, lb + j * GS);
    ga += 64; gb += 64;
    __syncthreads();  // barrier's vmcnt(0) drain makes DMA data visible

#pragma unroll
    for (int ks = 0; ks < 2; ks++) {
      bf16x8 af[4], bfv[4];
#pragma unroll
      for (int i = 0; i < 4; i++) {
        int R = wm + i * 16 + row;
        af[i] = *(const bf16x8*)&Al[(R >> 3) * GS + (R & 7) * 64 + (ks * 4 + quad) * 8];
      }
#pragma unroll
      for (int i = 0; i < 4; i++) {
        int R = wn + i * 16 + row;
        bfv[i] = *(const bf16x8*)&Bl[(R >> 3) * GS + (R & 7) * 64 + (ks * 4 + quad) * 8];
      }
#pragma unroll
      for (int i = 0; i < 4; i++)
#pragma unroll
        for (int j = 0; j < 4; j++)
          acc[i][j] = __builtin_amdgcn_mfma_f32_16x16x32_bf16(af[i], bfv[j], acc[i][j], 0, 0, 0);
    }
  }

  float g = SCALE ? gamma[0] : 1.0f;
  int col = lane & 15, rq = (lane >> 4) * 4;  // C/D: col=lane&15, row=quad*4+reg
#pragma unroll
  for (int i = 0; i < 4; i++)
#pragma unroll
    for (int j = 0; j < 4; j++)
#pragma unroll
      for (int r = 0; r < 4; r++) {
        int m = tm * 128 + wm + i * 16 + rq + r;
        int n = tn * 128 + wn + j * 16 + col;
        if (KSPLIT > 1)
          atomicAdd(&Cb[(size_t)m * N + n], acc[i][j][r]);
        else
          Cb[(size_t)m * N + n] = g * acc[i][j][r];
      }
}

// ---------------- kernel 4: row softmax fp32 -> bf16 ----------------
__global__ __launch_bounds__(256) void k_softmax(const float* __restrict__ S,
                                                 short* __restrict__ P) {
  size_t row = blockIdx.x;
  const float* s = S + row * CDIM;
  short* p = P + row * CDIM;
  int tid = threadIdx.x;
  float v0 = s[tid], v1 = s[tid + 256], v2 = s[tid + 512];
  float m = fmaxf(fmaxf(v0, v1), v2);
#pragma unroll
  for (int o = 32; o; o >>= 1) m = fmaxf(m, __shfl_xor(m, o, 64));
  __shared__ float rmax[4], rsum[4];
  if ((tid & 63) == 0) rmax[tid >> 6] = m;
  __syncthreads();
  m = fmaxf(fmaxf(rmax[0], rmax[1]), fmaxf(rmax[2], rmax[3]));
  float e0 = __expf(v0 - m), e1 = __expf(v1 - m), e2 = __expf(v2 - m);
  float su = e0 + e1 + e2;
#pragma unroll
  for (int o = 32; o; o >>= 1) su += __shfl_xor(su, o, 64);
  if ((tid & 63) == 0) rsum[tid >> 6] = su;
  __syncthreads();
  float inv = 1.0f / (rsum[0] + rsum[1] + rsum[2] + rsum[3]);
  p[tid]       = f2bf(e0 * inv);
  p[tid + 256] = f2bf(e1 * inv);
  p[tid + 512] = f2bf(e2 * inv);
}

extern "C" void kernel_launch(void* const* d_in, const int* in_sizes, int n_in,
                              void* d_out, int out_size, void* d_ws, size_t ws_size,
                              hipStream_t stream) {
  const float* x     = (const float*)d_in[0];
  const float* gamma = (const float*)d_in[1];
  float* out = (float*)d_out;

  // workspace layout (150 MiB), proven in R1/R3:
  //   [0, 100663296)         : Xb bf16 (phase 1) / XT bf16 (phase 2)
  //   [100663296, +37748736) : S fp32 [16][768][768]
  //   [+, +18874368)         : P bf16 [16][768][768]
  char* ws = (char*)d_ws;
  short* Xb = (short*)ws;
  float* S  = (float*)(ws + 100663296);
  short* P  = (short*)(ws + 100663296 + 37748736);

  // 1) X -> bf16 (row-major)
  {
    size_t total = (size_t)BATCH * CDIM * NDIM;  // 50331648
    k_cvt<<<(int)(total / (256 * 16)), 256, 0, stream>>>(x, Xb);
  }
  // 1b) S = 0 (split-K accumulates atomically)
  {
    size_t stot = (size_t)BATCH * CDIM * CDIM;   // 9437184
    k_zero<<<(int)(stot / (256 * 16)), 256, 0, stream>>>(S);
  }
  // 2) S += Xb * Xb^T  (M=N=768, K=4096, split-K x4)
  k_gemm<CDIM, CDIM, NDIM, 4, false>
      <<<dim3(6, 6, BATCH * 4), 256, 0, stream>>>(Xb, Xb, S, nullptr);
  // 3) P = softmax_rows(S), bf16
  k_softmax<<<BATCH * CDIM, 256, 0, stream>>>(S, P);
  // 4) XT = transpose(X) in bf16 (overwrites Xb region; Xb dead after step 2)
  k_transpose<<<dim3(NDIM / 64, CDIM / 64, BATCH), 256, 0, stream>>>(x, Xb);
  // 5) out = gamma * (P * XT^T)  (M=768, N=4096, K=768)
  k_gemm<CDIM, NDIM, CDIM, 1, true>
      <<<dim3(32, 6, BATCH), 256, 0, stream>>>(P, Xb, out, gamma);
}

// Round 5
// 649.466 us; speedup vs baseline: 1.0901x; 1.0901x over previous
//
#include <hip/hip_runtime.h>
#include <hip/hip_bf16.h>

// Shapes: B=16, C=768, HW=4096.
#define BATCH 16
#define CDIM 768
#define NDIM 4096

typedef float  floatx4 __attribute__((ext_vector_type(4)));
typedef short  bf16x8  __attribute__((ext_vector_type(8)));

__device__ __forceinline__ short f2bf(float f) {
  unsigned u = __float_as_uint(f);
  unsigned r = (u + 0x7FFFu + ((u >> 16) & 1u)) >> 16;  // RNE
  return (short)r;
}

// async global->LDS, 16B per lane. LDS dest = wave-uniform base + lane*16.
__device__ __forceinline__ void gl_lds16(const short* g, short* l) {
  __builtin_amdgcn_global_load_lds(
      (const __attribute__((address_space(1))) unsigned int*)g,
      (__attribute__((address_space(3))) unsigned int*)l, 16, 0, 0);
}

// ---------------- kernel 1: fp32 -> bf16 elementwise ----------------
__global__ __launch_bounds__(256) void k_cvt(const float* __restrict__ x,
                                             short* __restrict__ xb) {
  size_t i = ((size_t)blockIdx.x * 256 + threadIdx.x) * 16;
  const floatx4* src = (const floatx4*)(x + i);
  floatx4 f0 = src[0], f1 = src[1], f2 = src[2], f3 = src[3];
  bf16x8 lo, hi;
#pragma unroll
  for (int j = 0; j < 4; j++) {
    lo[j]     = f2bf(f0[j]);
    lo[j + 4] = f2bf(f1[j]);
    hi[j]     = f2bf(f2[j]);
    hi[j + 4] = f2bf(f3[j]);
  }
  *(bf16x8*)(xb + i)     = lo;
  *(bf16x8*)(xb + i + 8) = hi;
}

// ---------------- kernel 2: tiled transpose fp32 -> bf16 ----------------
__global__ __launch_bounds__(256) void k_transpose(const float* __restrict__ X,
                                                   short* __restrict__ XT) {
  __shared__ __align__(16) short T[64][72];  // +8 pad
  int b = blockIdx.z;
  const float* Xb = X + (size_t)b * CDIM * NDIM;
  short* XTb = XT + (size_t)b * NDIM * CDIM;
  int r  = threadIdx.x >> 2;   // 0..63
  int cq = threadIdx.x & 3;    // 0..3 (16-col chunk)
  int gr  = blockIdx.y * 64 + r;         // c index
  int gc0 = blockIdx.x * 64 + cq * 16;   // n index base
  const floatx4* src = (const floatx4*)(Xb + (size_t)gr * NDIM + gc0);
  floatx4 f0 = src[0], f1 = src[1], f2 = src[2], f3 = src[3];
  bf16x8 lo, hi;
#pragma unroll
  for (int j = 0; j < 4; j++) {
    lo[j] = f2bf(f0[j]); lo[j + 4] = f2bf(f1[j]);
    hi[j] = f2bf(f2[j]); hi[j + 4] = f2bf(f3[j]);
  }
  *(bf16x8*)&T[r][cq * 16]     = lo;
  *(bf16x8*)&T[r][cq * 16 + 8] = hi;
  __syncthreads();
  bf16x8 o0, o1;
#pragma unroll
  for (int j = 0; j < 8; j++) o0[j] = T[cq * 16 + j][r];
#pragma unroll
  for (int j = 0; j < 8; j++) o1[j] = T[cq * 16 + 8 + j][r];
  short* dst = XTb + (size_t)(blockIdx.x * 64 + r) * CDIM + blockIdx.y * 64 + cq * 16;
  *(bf16x8*)dst       = o0;
  *(bf16x8*)(dst + 8) = o1;
}

// ---------------- kernel 3: bt-GEMM, 128x128 tile, BK=64, DMA, XCD-pinned --
// C[m][n] = scale * sum_k A[m][k] * Bt[n][k]   (per batch)
// Grid is dim3(8, 2*TM*TN, 1). Linear workgroup id is x-fastest and XCD
// assignment is round-robin mod 8, so blockIdx.x pins the XCD. Each XCD owns
// batches {x, x+8}; all blocks of a batch share one 4 MiB L2, progress
// through K in rough lockstep -> per-k-slice working set ~100s of KB -> each
// input byte should be fetched from HBM ~once (attacks the 3.8x over-fetch).
// Within an XCD, order is tn-major-outer via r%TM / r/TM so blocks sharing a
// B-strip run adjacently.
// LDS: 8-row groups of 1024 B (DMA-contiguous), +64 B pad between groups
// (stride 544 shorts): conflict level measured at the b128 floor (R4).
template <int M, int N, int K, int TM, int TN, bool SCALE>
__global__ __launch_bounds__(256) void k_gemm(const short* __restrict__ A,
                                              const short* __restrict__ Bt,
                                              float* __restrict__ C,
                                              const float* __restrict__ gamma) {
  constexpr int GS = 544;   // shorts per 8-row group (1024 B + 64 B pad)
  constexpr int PB = TM * TN;
  __shared__ __align__(16) short Al[16 * GS];
  __shared__ __align__(16) short Bl[16 * GS];

  int xcd = blockIdx.x;                 // 0..7
  int y   = blockIdx.y;                 // 0..2*PB-1
  int b   = xcd + 8 * (y / PB);         // batch pinned to this XCD
  int r   = y % PB;
  int tm  = r % TM;
  int tn  = r / TM;

  const short* Ab = A  + (size_t)b * M * K;
  const short* Bb = Bt + (size_t)b * N * K;
  float* Cb = C + (size_t)b * M * N;

  int tid  = threadIdx.x;
  int lane = tid & 63;
  int wave = tid >> 6;
  int wm = (wave >> 1) * 64;
  int wn = (wave & 1) * 64;

  // DMA: wave covers rows [wave*32, +32) = groups [wave*4, +4), 4 issues.
  int lr = lane >> 3;    // row within 8-row issue
  int lc = lane & 7;     // 16B chunk within row
  const short* ga = Ab + (size_t)(tm * 128 + wave * 32 + lr) * K + lc * 8;
  const short* gb = Bb + (size_t)(tn * 128 + wave * 32 + lr) * K + lc * 8;
  short* la = Al + wave * 4 * GS;
  short* lb = Bl + wave * 4 * GS;

  floatx4 acc[4][4] = {};
  int row = lane & 15, quad = lane >> 4;

  for (int k0 = 0; k0 < K; k0 += 64) {
    __syncthreads();  // previous iter's ds_reads done before overwrite
#pragma unroll
    for (int j = 0; j < 4; j++)
      gl_lds16(ga + (size_t)j * 8 * K, la + j * GS);
#pragma unroll
    for (int j = 0; j < 4; j++)
      gl_lds16(gb + (size_t)j * 8 * K, lb + j * GS);
    ga += 64; gb += 64;
    __syncthreads();  // barrier's vmcnt(0) drain makes DMA data visible

#pragma unroll
    for (int ks = 0; ks < 2; ks++) {
      bf16x8 af[4], bfv[4];
#pragma unroll
      for (int i = 0; i < 4; i++) {
        int R = wm + i * 16 + row;
        af[i] = *(const bf16x8*)&Al[(R >> 3) * GS + (R & 7) * 64 + (ks * 4 + quad) * 8];
      }
#pragma unroll
      for (int i = 0; i < 4; i++) {
        int R = wn + i * 16 + row;
        bfv[i] = *(const bf16x8*)&Bl[(R >> 3) * GS + (R & 7) * 64 + (ks * 4 + quad) * 8];
      }
#pragma unroll
      for (int i = 0; i < 4; i++)
#pragma unroll
        for (int j = 0; j < 4; j++)
          acc[i][j] = __builtin_amdgcn_mfma_f32_16x16x32_bf16(af[i], bfv[j], acc[i][j], 0, 0, 0);
    }
  }

  float g = SCALE ? gamma[0] : 1.0f;
  int col = lane & 15, rq = (lane >> 4) * 4;  // C/D: col=lane&15, row=quad*4+reg
#pragma unroll
  for (int i = 0; i < 4; i++)
#pragma unroll
    for (int j = 0; j < 4; j++)
#pragma unroll
      for (int rr = 0; rr < 4; rr++) {
        int m = tm * 128 + wm + i * 16 + rq + rr;
        int n = tn * 128 + wn + j * 16 + col;
        Cb[(size_t)m * N + n] = g * acc[i][j][rr];
      }
}

// ---------------- kernel 4: row softmax fp32 -> bf16 ----------------
__global__ __launch_bounds__(256) void k_softmax(const float* __restrict__ S,
                                                 short* __restrict__ P) {
  size_t row = blockIdx.x;
  const float* s = S + row * CDIM;
  short* p = P + row * CDIM;
  int tid = threadIdx.x;
  float v0 = s[tid], v1 = s[tid + 256], v2 = s[tid + 512];
  float m = fmaxf(fmaxf(v0, v1), v2);
#pragma unroll
  for (int o = 32; o; o >>= 1) m = fmaxf(m, __shfl_xor(m, o, 64));
  __shared__ float rmax[4], rsum[4];
  if ((tid & 63) == 0) rmax[tid >> 6] = m;
  __syncthreads();
  m = fmaxf(fmaxf(rmax[0], rmax[1]), fmaxf(rmax[2], rmax[3]));
  float e0 = __expf(v0 - m), e1 = __expf(v1 - m), e2 = __expf(v2 - m);
  float su = e0 + e1 + e2;
#pragma unroll
  for (int o = 32; o; o >>= 1) su += __shfl_xor(su, o, 64);
  if ((tid & 63) == 0) rsum[tid >> 6] = su;
  __syncthreads();
  float inv = 1.0f / (rsum[0] + rsum[1] + rsum[2] + rsum[3]);
  p[tid]       = f2bf(e0 * inv);
  p[tid + 256] = f2bf(e1 * inv);
  p[tid + 512] = f2bf(e2 * inv);
}

extern "C" void kernel_launch(void* const* d_in, const int* in_sizes, int n_in,
                              void* d_out, int out_size, void* d_ws, size_t ws_size,
                              hipStream_t stream) {
  const float* x     = (const float*)d_in[0];
  const float* gamma = (const float*)d_in[1];
  float* out = (float*)d_out;

  // workspace layout (150 MiB), proven in R1/R3/R4:
  //   [0, 100663296)         : Xb bf16 (phase 1) / XT bf16 (phase 2)
  //   [100663296, +37748736) : S fp32 [16][768][768]
  //   [+, +18874368)         : P bf16 [16][768][768]
  char* ws = (char*)d_ws;
  short* Xb = (short*)ws;
  float* S  = (float*)(ws + 100663296);
  short* P  = (short*)(ws + 100663296 + 37748736);

  // 1) X -> bf16 (row-major)
  {
    size_t total = (size_t)BATCH * CDIM * NDIM;  // 50331648
    k_cvt<<<(int)(total / (256 * 16)), 256, 0, stream>>>(x, Xb);
  }
  // 2) S = Xb * Xb^T  (M=N=768, K=4096), XCD-pinned: 8 x 72 blocks
  k_gemm<CDIM, CDIM, NDIM, 6, 6, false>
      <<<dim3(8, 2 * 6 * 6, 1), 256, 0, stream>>>(Xb, Xb, S, nullptr);
  // 3) P = softmax_rows(S), bf16
  k_softmax<<<BATCH * CDIM, 256, 0, stream>>>(S, P);
  // 4) XT = transpose(X) in bf16 (overwrites Xb region; Xb dead after step 2)
  k_transpose<<<dim3(NDIM / 64, CDIM / 64, BATCH), 256, 0, stream>>>(x, Xb);
  // 5) out = gamma * (P * XT^T)  (M=768, N=4096, K=768), XCD-pinned: 8 x 384
  k_gemm<CDIM, NDIM, CDIM, 6, 32, true>
      <<<dim3(8, 2 * 6 * 32, 1), 256, 0, stream>>>(P, Xb, out, gamma);
}